// Round 2
// baseline (690.003 us; speedup 1.0000x reference)
//
#include <hip/hip_runtime.h>

// Local2d: out[b,o,h,w] = sum_{i,ky,kx} weight[o,h,w,i,ky,kx]*xpad[b,i,h+ky-1,w+kx-1] + bias[o,h,w]
// B=64, C_IN=64, C_OUT=128, K=3, H=W=32.
//
// Per-location GEMM: M=64 (batch), Kdim=576. Grid 2048 = 1024 loc x 2 o-groups
// (N=64 couts per block). K in 2 chunks of 288 (32 input channels).
// Both A (patches) and W staged in LDS in MFMA fragment order as bf16;
// W staging is COALESCED (contiguous weight rows) -> the K-loop is LDS-only.
// mfma_f32_16x16x32_bf16; each wave: m-tile = wave id, all 4 n-tiles.

typedef __bf16  bf16x8  __attribute__((ext_vector_type(8)));
typedef float   floatx4 __attribute__((ext_vector_type(4)));

static __device__ inline bf16x8 cvt8(floatx4 a, floatx4 b) {
    bf16x8 r;
    r[0] = (__bf16)a[0]; r[1] = (__bf16)a[1]; r[2] = (__bf16)a[2]; r[3] = (__bf16)a[3];
    r[4] = (__bf16)b[0]; r[5] = (__bf16)b[1]; r[6] = (__bf16)b[2]; r[7] = (__bf16)b[3];
    return r;
}

__global__ __launch_bounds__(256, 2) void local2d_kernel(
    const float* __restrict__ x,       // [64,64,32,32]
    const float* __restrict__ weight,  // [128,32,32,64,3,3]
    const float* __restrict__ bias,    // [128,32,32]
    float* __restrict__ out)           // [64,128,32,32]
{
    // A fragments: [tc 9][mt 4][lane 64][j 8] bf16 = 36,864 B
    __shared__ __bf16 alds[9 * 4 * 64 * 8];
    // W fragments: idx16 = (t*4+nt)*65 + lane (65-pad kills bank conflicts)
    __shared__ __bf16 wlds[36 * 65 * 8];   // 37,440 B

    const int tid  = threadIdx.x;
    const int lane = tid & 63;
    const int wv   = tid >> 6;          // wave = m-tile
    const int ll   = lane & 15;
    const int q    = lane >> 4;

    const int bid = blockIdx.x;
    const int loc = bid >> 1;           // 0..1023
    const int og  = bid & 1;            // o-group: couts [og*64, og*64+64)
    const int h = loc >> 5, w = loc & 31;

    floatx4 acc[4];
    #pragma unroll
    for (int nt = 0; nt < 4; ++nt) acc[nt] = (floatx4){0.f, 0.f, 0.f, 0.f};

    for (int c = 0; c < 2; ++c) {
        // ---- stage A chunk c: i in [c*32, c*32+32), fragment order ----
        #pragma unroll
        for (int pp = 0; pp < 8; ++pp) {
            int p  = tid + (pp << 8);
            int b  = p >> 5;
            int il = p & 31;
            int i  = (c << 5) | il;
            int kbase = il * 9;
            const float* xp = x + ((size_t)b * 64 + i) * 1024;
            int mt      = b >> 4;
            int lane_lo = b & 15;
            #pragma unroll
            for (int ky = 0; ky < 3; ++ky) {
                int y = h + ky - 1;
                bool yok = (unsigned)y < 32u;
                #pragma unroll
                for (int kx = 0; kx < 3; ++kx) {
                    int xc = w + kx - 1;
                    float v = (yok && (unsigned)xc < 32u) ? xp[y * 32 + xc] : 0.0f;
                    int kd = kbase + ky * 3 + kx;      // 0..287
                    int tc = kd >> 5;
                    int r  = kd & 31;
                    int lw = ((r >> 3) << 4) | lane_lo;
                    int j  = r & 7;
                    alds[((((tc << 2) + mt) << 6) | lw) * 8 + j] = (__bf16)v;
                }
            }
        }

        // ---- stage W chunk c (coalesced): rows o = og*64+ol, k in [c*288,+288) ----
        // 64 rows x 36 j-groups = 2304 groups = 9 iters x 256 threads (exact)
        {
            const float* wbase = weight + ((size_t)(og * 64) * 1024 + loc) * 576 + c * 288;
            #pragma unroll
            for (int it = 0; it < 9; ++it) {
                int g  = tid + (it << 8);
                int ol = g / 36;                  // 0..63  (magic-mul)
                int jg = g - ol * 36;             // 0..35
                const floatx4* src = (const floatx4*)(wbase + (size_t)ol * 589824 + jg * 8);
                floatx4 va = src[0];
                floatx4 vb = src[1];
                int t  = jg >> 2;
                int qq = jg & 3;
                int nt = ol >> 4;
                int lll = ol & 15;
                int idx16 = ((t << 2) + nt) * 65 + (qq << 4) + lll;
                *(bf16x8*)&wlds[idx16 * 8] = cvt8(va, vb);
            }
        }
        __syncthreads();

        // ---- K loop: LDS-only, 9 steps of K=32 ----
        #pragma unroll 3
        for (int t = 0; t < 9; ++t) {
            bf16x8 af = *(const bf16x8*)&alds[((((t << 2) + wv) << 6) | lane) * 8];
            #pragma unroll
            for (int nt = 0; nt < 4; ++nt) {
                bf16x8 bw = *(const bf16x8*)&wlds[(((t << 2) + nt) * 65 + lane) * 8];
                acc[nt] = __builtin_amdgcn_mfma_f32_16x16x32_bf16(af, bw, acc[nt], 0, 0, 0);
            }
        }
        __syncthreads();
    }

    // ---- epilogue: bias + store (C/D: col=lane&15 -> o, row=q*4+r -> b) ----
    #pragma unroll
    for (int nt = 0; nt < 4; ++nt) {
        int o = (og << 6) + (nt << 4) + ll;
        float bv = bias[(size_t)o * 1024 + loc];
        #pragma unroll
        for (int r = 0; r < 4; ++r) {
            int m = (wv << 4) + (q << 2) + r;
            out[((size_t)m * 128 + o) * 1024 + loc] = acc[nt][r] + bv;
        }
    }
}

extern "C" void kernel_launch(void* const* d_in, const int* in_sizes, int n_in,
                              void* d_out, int out_size, void* d_ws, size_t ws_size,
                              hipStream_t stream) {
    const float* x  = (const float*)d_in[0];
    const float* wt = (const float*)d_in[1];
    const float* bi = (const float*)d_in[2];
    float* out = (float*)d_out;
    local2d_kernel<<<dim3(2048), dim3(256), 0, stream>>>(x, wt, bi, out);
}

// Round 3
// 506.670 us; speedup vs baseline: 1.3618x; 1.3618x over previous
//
#include <hip/hip_runtime.h>

// Local2d: out[b,o,h,w] = sum_{i,ky,kx} weight[o,h,w,i,ky,kx]*xpad[b,i,h+ky-1,w+kx-1] + bias
// B=64, C_IN=64, C_OUT=128, K=3, H=W=32.
//
// Two kernels:
//  1) prep_kernel (im2col): x -> P in d_ws. P[loc][tc 18][mt 4][lane 64][j 8] bf16
//     (75.5 MB), i.e. the exact MFMA A-fragment byte order for k = i*9+ky*3+kx.
//     Reads x coalesced (float4 rows through LDS), writes dense 256 B chunks.
//  2) local2d_kernel: per-(loc, o-group) GEMM M=64,N=64,K=576 in 3 chunks of 192.
//     A-stage: contiguous global_load_lds dwordx4 from P (no gather, no VGPRs).
//     W-stage: coalesced float4 rows -> cvt bf16 -> LDS fragments.
//     LDS 49.5 KB -> 3 blocks/CU. XCD swizzle: h-row group per XCD so the 16
//     blocks sharing each 64 B out-line merge in one L2 (R1 evidence: 68 MB writes).

typedef __bf16  bf16x8  __attribute__((ext_vector_type(8)));
typedef float   floatx4 __attribute__((ext_vector_type(4)));

static __device__ inline bf16x8 cvt8(floatx4 a, floatx4 b) {
    bf16x8 r;
    r[0] = (__bf16)a[0]; r[1] = (__bf16)a[1]; r[2] = (__bf16)a[2]; r[3] = (__bf16)a[3];
    r[4] = (__bf16)b[0]; r[5] = (__bf16)b[1]; r[6] = (__bf16)b[2]; r[7] = (__bf16)b[3];
    return r;
}

// ---------------- im2col prep ----------------
// grid 1024 = h(32) x ig(8) x bq(4); block 256.
// Block stages x[b=bq*16..+16, i=ig*8..+8, y=h-1..h+1, :] (48 KB, coalesced),
// then emits 16 B "pieces": P piece (loc, ko, b) = bf16 x8 for k=ko*8..+8.
__global__ __launch_bounds__(256, 3) void prep_kernel(
    const float* __restrict__ x, __bf16* __restrict__ P)
{
    __shared__ float xl[16 * 772];   // [bl][il*96 + ky*32 + w], bl-stride 772 (align+bank)

    const int tid = threadIdx.x;
    const int bid = blockIdx.x;
    const int bq = bid & 3;          // mt  (b = bq*16 + bl)
    const int ig = (bid >> 2) & 7;   // i-group of 8 -> 9 k-octets
    const int h  = bid >> 5;

    // stage 384 rows of 32 floats (zeros for OOB y)
    #pragma unroll
    for (int it = 0; it < 12; ++it) {
        int g   = tid + (it << 8);       // 0..3071
        int row = g >> 3;                // 0..383 = bl*24 + il*3 + ky
        int sub = g & 7;
        int bl  = row / 24;
        int rem = row - bl * 24;
        int il  = rem / 3;
        int ky  = rem - il * 3;
        int y   = h + ky - 1;
        floatx4 v = {0.f, 0.f, 0.f, 0.f};
        if ((unsigned)y < 32u) {
            const float* src = x + (((size_t)(bq * 16 + bl) * 64 + ig * 8 + il) << 10)
                                 + y * 32 + (sub << 2);
            v = *(const floatx4*)src;
        }
        *(floatx4*)&xl[bl * 772 + il * 96 + ky * 32 + (sub << 2)] = v;
    }
    __syncthreads();

    const int lane = tid & 63;
    const int wv = tid >> 6;
    const int bl = lane & 15;
    const int qq = lane >> 4;

    // 288 (w,kol) pairs x 16 bl; 16 pairs per iter (4 waves x 4 quads)
    #pragma unroll 2
    for (int it = 0; it < 18; ++it) {
        int pr  = (it << 4) + (wv << 2) + qq;   // 0..287
        int w   = pr / 9;
        int kol = pr - w * 9;                   // 0..8
        int ko  = ig * 9 + kol;                 // global k-octet 0..71
        bf16x8 piece;
        #pragma unroll
        for (int j = 0; j < 8; ++j) {
            int klocal = (kol << 3) + j;        // 0..71 within i-group
            int il = klocal / 9;
            int p  = klocal - il * 9;
            int ky = p / 3;
            int kx = p - ky * 3;
            int xc = w + kx - 1;
            float v = ((unsigned)xc < 32u) ? xl[bl * 772 + il * 96 + ky * 32 + xc] : 0.0f;
            piece[j] = (__bf16)v;
        }
        int loc   = (h << 5) + w;
        int idx16 = ((ko >> 2) << 8) + (bq << 6) + ((ko & 3) << 4) + bl;
        *(bf16x8*)&P[((size_t)loc * 4608 + idx16) * 8] = piece;
    }
}

// ---------------- main GEMM ----------------
__global__ __launch_bounds__(256, 3) void local2d_kernel(
    const __bf16* __restrict__ P,      // patches, fragment layout
    const float* __restrict__ weight,  // [128,32,32,64,3,3]
    const float* __restrict__ bias,    // [128,32,32]
    float* __restrict__ out)           // [64,128,32,32]
{
    __shared__ __bf16 alds[6 * 4 * 64 * 8];   // 24,576 B
    __shared__ __bf16 wlds[24 * 65 * 8];      // 24,960 B

    const int tid  = threadIdx.x;
    const int lane = tid & 63;
    const int wv   = tid >> 6;      // m-tile
    const int ll   = lane & 15;
    const int q    = lane >> 4;

    // bid = [hl 2][w 5][og 1][xcd 3]: XCD owns 4 h-rows; line-mates co-XCD.
    const int bid = blockIdx.x;
    const int xcd = bid & 7;
    const int og  = (bid >> 3) & 1;
    const int w   = (bid >> 4) & 31;
    const int hl  = bid >> 9;
    const int h   = (xcd << 2) + hl;
    const int loc = (h << 5) + w;

    const __bf16* Ploc  = P + (size_t)loc * 36864;   // 36,864 bf16 per loc
    const float*  wbase = weight + ((size_t)(og << 6) * 1024 + loc) * 576;

    floatx4 acc[4];
    #pragma unroll
    for (int nt = 0; nt < 4; ++nt) acc[nt] = (floatx4){0.f, 0.f, 0.f, 0.f};

    for (int c = 0; c < 3; ++c) {
        // ---- A-stage: async contiguous copy of 24,576 B from P ----
        #pragma unroll
        for (int it = 0; it < 6; ++it) {
            const __bf16* g = Ploc + c * 12288 + ((((it << 2) + wv) << 6) | lane) * 8;
            __builtin_amdgcn_global_load_lds(
                (const __attribute__((address_space(1))) unsigned int*)g,
                (__attribute__((address_space(3))) unsigned int*)&alds[(((it << 2) + wv) << 6) * 8],
                16, 0, 0);
        }
        // ---- W-stage: 64 rows x 192 k, coalesced ----
        #pragma unroll
        for (int it = 0; it < 6; ++it) {
            int g  = tid + (it << 8);       // 0..1535
            int ol = g / 24;
            int jg = g - ol * 24;           // 0..23
            const float* src = wbase + (size_t)ol * 589824 + c * 192 + (jg << 3);
            floatx4 va = *(const floatx4*)src;
            floatx4 vb = *(const floatx4*)(src + 4);
            int t  = jg >> 2;
            int qw = jg & 3;
            int nt = ol >> 4;
            int lw = ol & 15;
            *(bf16x8*)&wlds[(((t << 2) + nt) * 65 + (qw << 4) + lw) * 8] = cvt8(va, vb);
        }
        __syncthreads();

        // ---- K loop: 6 steps of K=32, LDS-only ----
        #pragma unroll
        for (int t = 0; t < 6; ++t) {
            bf16x8 af = *(const bf16x8*)&alds[((((t << 2) + wv) << 6) | lane) * 8];
            #pragma unroll
            for (int nt = 0; nt < 4; ++nt) {
                bf16x8 bw = *(const bf16x8*)&wlds[(((t << 2) + nt) * 65 + lane) * 8];
                acc[nt] = __builtin_amdgcn_mfma_f32_16x16x32_bf16(af, bw, acc[nt], 0, 0, 0);
            }
        }
        __syncthreads();
    }

    // ---- epilogue: C/D col=lane&15 -> o, row=q*4+r -> b ----
    #pragma unroll
    for (int nt = 0; nt < 4; ++nt) {
        int o = (og << 6) + (nt << 4) + ll;
        float bv = bias[((size_t)o << 10) + loc];
        #pragma unroll
        for (int r = 0; r < 4; ++r) {
            int m = (wv << 4) + (q << 2) + r;
            out[(((size_t)m << 7) + o) * 1024 + loc] = acc[nt][r] + bv;
        }
    }
}

extern "C" void kernel_launch(void* const* d_in, const int* in_sizes, int n_in,
                              void* d_out, int out_size, void* d_ws, size_t ws_size,
                              hipStream_t stream) {
    const float* x  = (const float*)d_in[0];
    const float* wt = (const float*)d_in[1];
    const float* bi = (const float*)d_in[2];
    float* out = (float*)d_out;
    __bf16* P = (__bf16*)d_ws;   // needs 75,497,472 B
    prep_kernel<<<dim3(1024), dim3(256), 0, stream>>>(x, P);
    local2d_kernel<<<dim3(2048), dim3(256), 0, stream>>>(P, wt, bi, out);
}